// Round 14
// baseline (231.231 us; speedup 1.0000x reference)
//
#include <hip/hip_runtime.h>

#define T_TOK 1024
#define NEXP 8
#define HID 1024
#define INTER 2048
#define SLOT_CAP 2176
#define NSLOT 2048
#define MAXTILES 24  // sum ceil(n_e/128) <= 16 + 7 = 23

#define BK 32
#define LDK 40  // padded K stride in LDS (bf16 elems): 80B rows
#define SPLITK 2
#define KCHUNK (INTER / SPLITK)  // 1024

typedef __bf16 bf16x8 __attribute__((ext_vector_type(8)));
typedef __bf16 bf16x4 __attribute__((ext_vector_type(4)));
typedef float f32x4 __attribute__((ext_vector_type(4)));

// ---- workspace layout (bytes) ----
#define WS_COUNTS 0
#define WS_OFFSETS 64
#define WS_TEXPERT 128
#define WS_TGATE (WS_TEXPERT + T_TOK * 2 * 4)
#define WS_TRANK (WS_TGATE + T_TOK * 2 * 4)
#define WS_TOKEN_OF (WS_TRANK + T_TOK * 2 * 4)
#define WS_GATE_OF (WS_TOKEN_OF + SLOT_CAP * 4)
#define WS_SLOT_OF (WS_GATE_OF + SLOT_CAP * 4)
#define WS_TILE_E (WS_SLOT_OF + T_TOK * 2 * 4)
#define WS_TILE_R (WS_TILE_E + 256)
#define WS_NTILES (WS_TILE_R + 256)
#define WS_ABUF 65536                           // bf16 a[SLOT_CAP][INTER]
#define WS_YS (WS_ABUF + SLOT_CAP * INTER * 2)  // fp32 ys[SPLITK][NSLOT][HID]
// xg (bf16 [SLOT_CAP][HID]) aliases YS: consumed by gemm1 before gemm2 writes ys.

// ---------------- router: softmax + top-2 ----------------
__global__ void moe_router(const float* __restrict__ logits, int* __restrict__ counts,
                           int* __restrict__ t_expert, float* __restrict__ t_gate,
                           int* __restrict__ t_rank) {
  int t = blockIdx.x * blockDim.x + threadIdx.x;
  if (t >= T_TOK) return;
  float l[NEXP];
  float mx = -1e30f;
#pragma unroll
  for (int e = 0; e < NEXP; ++e) {
    l[e] = logits[t * NEXP + e];
    mx = fmaxf(mx, l[e]);
  }
  float s = 0.f;
#pragma unroll
  for (int e = 0; e < NEXP; ++e) {
    l[e] = __expf(l[e] - mx);
    s += l[e];
  }
  float inv = 1.f / s;
  int i0 = 0;
#pragma unroll
  for (int e = 1; e < NEXP; ++e)
    if (l[e] > l[i0]) i0 = e;
  int i1 = (i0 == 0) ? 1 : 0;
#pragma unroll
  for (int e = 0; e < NEXP; ++e)
    if (e != i0 && e != i1 && l[e] > l[i1]) i1 = e;
  int es[2] = {i0, i1};
#pragma unroll
  for (int k = 0; k < 2; ++k) {
    int e = es[k];
    int r = atomicAdd(&counts[e], 1);
    int p = t * 2 + k;
    t_expert[p] = e;
    t_gate[p] = l[e] * inv;
    t_rank[p] = r;
  }
}

// ---------------- assign ----------------
__global__ void moe_assign(const int* __restrict__ counts, int* __restrict__ offsets,
                           const int* __restrict__ t_expert, const float* __restrict__ t_gate,
                           const int* __restrict__ t_rank, int* __restrict__ token_of,
                           float* __restrict__ gate_of, int* __restrict__ slot_of,
                           int* __restrict__ tile_e, int* __restrict__ tile_r,
                           int* __restrict__ n_tiles) {
  __shared__ int off_s[NEXP];
  if (threadIdx.x == 0) {
    int s = 0, nt = 0;
    for (int e = 0; e < NEXP; ++e) {
      off_s[e] = s;
      offsets[e] = s;
      int ntile = (counts[e] + 127) >> 7;
      for (int r = 0; r < ntile; ++r) {
        tile_e[nt] = e;
        tile_r[nt] = r;
        ++nt;
      }
      s += counts[e];
    }
    *n_tiles = nt;
  }
  __syncthreads();
  for (int p = threadIdx.x; p < T_TOK * 2; p += blockDim.x) {
    int e = t_expert[p];
    int slot = off_s[e] + t_rank[p];
    token_of[slot] = p >> 1;
    gate_of[slot] = t_gate[p];
    slot_of[p] = slot;
  }
}

// ---------------- xgather ----------------
__global__ void moe_xgather(const float* __restrict__ x, const int* __restrict__ token_of,
                            __bf16* __restrict__ xg) {
  int idx = blockIdx.x * blockDim.x + threadIdx.x;
  int slot = idx >> 7;
  int c = (idx & 127) * 8;
  const float* src = x + (size_t)token_of[slot] * HID + c;
  float4 v0 = *(const float4*)src;
  float4 v1 = *(const float4*)(src + 4);
  bf16x8 o = {(__bf16)v0.x, (__bf16)v0.y, (__bf16)v0.z, (__bf16)v0.w,
              (__bf16)v1.x, (__bf16)v1.y, (__bf16)v1.z, (__bf16)v1.w};
  *(bf16x8*)&xg[(size_t)slot * HID + c] = o;
}

#define TRANSPOSE_STORE(dst, r0, r1, r2, r3, cbase, kbase4)                    \
  {                                                                            \
    bf16x4 c0 = {(__bf16)r0.x, (__bf16)r1.x, (__bf16)r2.x, (__bf16)r3.x};      \
    bf16x4 c1 = {(__bf16)r0.y, (__bf16)r1.y, (__bf16)r2.y, (__bf16)r3.y};      \
    bf16x4 c2 = {(__bf16)r0.z, (__bf16)r1.z, (__bf16)r2.z, (__bf16)r3.z};      \
    bf16x4 c3 = {(__bf16)r0.w, (__bf16)r1.w, (__bf16)r2.w, (__bf16)r3.w};      \
    *(bf16x4*)&dst[(cbase) + 0][kbase4] = c0;                                  \
    *(bf16x4*)&dst[(cbase) + 1][kbase4] = c1;                                  \
    *(bf16x4*)&dst[(cbase) + 2][kbase4] = c2;                                  \
    *(bf16x4*)&dst[(cbase) + 3][kbase4] = c3;                                  \
  }

// ---------------- GEMM1 (ablation template) ----------------
// MODE 0: full (real pass).  MODE 1: no-MFMA (memory path only).
// MODE 2: no-global-loads (LDS+MFMA path only).
// V1/V2 write the same abuf footprint V0 overwrites afterwards -> output unchanged.
template <int MODE>
__global__ __launch_bounds__(256, 3) void moe_gemm1(
    const __bf16* __restrict__ xg, const float* __restrict__ w1, const float* __restrict__ w3,
    const int* __restrict__ offsets, const int* __restrict__ counts,
    const int* __restrict__ tile_e, const int* __restrict__ tile_r,
    const int* __restrict__ n_tiles, __bf16* __restrict__ abuf) {
  if ((int)blockIdx.y >= *n_tiles) return;
  const int e = tile_e[blockIdx.y];
  const int rt = tile_r[blockIdx.y];
  const int n_e = counts[e];
  const int off_e = offsets[e];
  const int col0 = blockIdx.x * 64;
  const int tid = threadIdx.x;
  const int lane = tid & 63;
  const int wid = tid >> 6;
  const int wr = (wid >> 1) * 64;
  const int wc = (wid & 1) * 32;

  __shared__ __bf16 aL[2][128][LDK];
  __shared__ __bf16 b1L[2][64][LDK];
  __shared__ __bf16 b3L[2][64][LDK];

  f32x4 acc_h[4][2], acc_u[4][2];
#pragma unroll
  for (int m = 0; m < 4; ++m)
#pragma unroll
    for (int n = 0; n < 2; ++n) {
      acc_h[m][n] = (f32x4){0.f, 0.f, 0.f, 0.f};
      acc_u[m][n] = (f32x4){0.f, 0.f, 0.f, 0.f};
    }
  float sink = 0.f;  // live-sink for V1 (prevents DCE of loads/reads; rule #17)

  const int arow = tid >> 1, achk = (tid & 1) * 16;
  const int r_loc_a = rt * 128 + arow;
  const int slot_a = off_e + (r_loc_a < n_e ? r_loc_a : n_e - 1);
  const __bf16* ap = xg + (size_t)slot_a * HID + achk;
  const int bsel = tid >> 7;
  const int sub = tid & 127;
  const int bcq = sub >> 3, bkq = sub & 7;
  const float* wp = (bsel ? w3 : w1) + (size_t)e * HID * INTER +
                    (size_t)(bkq * 4) * INTER + col0 + bcq * 4;

  const int lr = lane & 15, lg = lane >> 4;

  bf16x8 av[2] = {};
  float4 bv[4] = {};

#define G1_LOAD(K0)                                                            \
  {                                                                            \
    if constexpr (MODE != 2) {                                                 \
      av[0] = *(const bf16x8*)(ap + (K0));                                     \
      av[1] = *(const bf16x8*)(ap + (K0) + 8);                                 \
      const float* p = wp + (size_t)(K0)*INTER;                                \
      _Pragma("unroll") for (int r = 0; r < 4; ++r) bv[r] =                    \
          *(const float4*)(p + (size_t)r * INTER);                             \
    }                                                                          \
  }
#define G1_STORE(BUF)                                                          \
  {                                                                            \
    *(bf16x8*)&aL[BUF][arow][achk] = av[0];                                    \
    *(bf16x8*)&aL[BUF][arow][achk + 8] = av[1];                                \
    if (bsel == 0) {                                                           \
      TRANSPOSE_STORE(b1L[BUF], bv[0], bv[1], bv[2], bv[3], bcq * 4, bkq * 4); \
    } else {                                                                   \
      TRANSPOSE_STORE(b3L[BUF], bv[0], bv[1], bv[2], bv[3], bcq * 4, bkq * 4); \
    }                                                                          \
  }

  const int NT = HID / BK;  // 32
  G1_LOAD(0);
  G1_STORE(0);
  __syncthreads();
#pragma unroll 1
  for (int t = 0; t < NT; ++t) {
    const int cur = t & 1, nxt = cur ^ 1;
    if constexpr (MODE == 2) {  // perturb regs so LDS stores can't be hoisted
      av[0][0] = (__bf16)(float)t;
      bv[0].x = (float)t;
    }
    if (t + 1 < NT) G1_LOAD((t + 1) * BK);
    bf16x8 af[4], bf1[2], bf3[2];
#pragma unroll
    for (int m = 0; m < 4; ++m) af[m] = *(const bf16x8*)&aL[cur][wr + m * 16 + lr][lg * 8];
#pragma unroll
    for (int n = 0; n < 2; ++n) {
      bf1[n] = *(const bf16x8*)&b1L[cur][wc + n * 16 + lr][lg * 8];
      bf3[n] = *(const bf16x8*)&b3L[cur][wc + n * 16 + lr][lg * 8];
    }
    if constexpr (MODE == 1) {
      // consume frag reads cheaply; no MFMA
      sink += (float)af[0][0] + (float)af[1][0] + (float)af[2][0] + (float)af[3][0] +
              (float)bf1[0][0] + (float)bf1[1][0] + (float)bf3[0][0] + (float)bf3[1][0];
    } else {
#pragma unroll
      for (int m = 0; m < 4; ++m)
#pragma unroll
        for (int n = 0; n < 2; ++n) {
          acc_h[m][n] =
              __builtin_amdgcn_mfma_f32_16x16x32_bf16(af[m], bf1[n], acc_h[m][n], 0, 0, 0);
          acc_u[m][n] =
              __builtin_amdgcn_mfma_f32_16x16x32_bf16(af[m], bf3[n], acc_u[m][n], 0, 0, 0);
        }
    }
    if (t + 1 < NT) G1_STORE(nxt);
    __syncthreads();
  }
#undef G1_LOAD
#undef G1_STORE

  if (MODE == 1 && n_e < 0) abuf[0] = (__bf16)sink;  // never true; keeps sink live

#pragma unroll
  for (int m = 0; m < 4; ++m)
#pragma unroll
    for (int n = 0; n < 2; ++n) {
      int col = col0 + wc + n * 16 + lr;
#pragma unroll
      for (int r = 0; r < 4; ++r) {
        int row_loc = rt * 128 + wr + m * 16 + lg * 4 + r;
        if (row_loc < n_e) {
          float h = acc_h[m][n][r];
          float u = acc_u[m][n][r];
          float a = h / (1.f + __expf(-h)) * u;
          abuf[(size_t)(off_e + row_loc) * INTER + col] = (__bf16)a;
        }
      }
    }
}

// ---------------- GEMM2 (unchanged R10 structure) ----------------
__global__ __launch_bounds__(256, 4) void moe_gemm2(
    const __bf16* __restrict__ abuf, const float* __restrict__ w2,
    const int* __restrict__ offsets, const int* __restrict__ counts,
    const float* __restrict__ gate_of, const int* __restrict__ tile_e,
    const int* __restrict__ tile_r, const int* __restrict__ n_tiles,
    float* __restrict__ yslot) {
  if ((int)blockIdx.y >= *n_tiles) return;
  const int e = tile_e[blockIdx.y];
  const int rt = tile_r[blockIdx.y];
  const int sk = blockIdx.z;
  const int n_e = counts[e];
  const int off_e = offsets[e];
  const int col0 = blockIdx.x * 64;
  const int kbase = sk * KCHUNK;
  const int tid = threadIdx.x;
  const int lane = tid & 63;
  const int wid = tid >> 6;
  const int wr = (wid >> 1) * 64;
  const int wc = (wid & 1) * 32;

  __shared__ __bf16 aL[2][128][LDK];
  __shared__ __bf16 bL[2][64][LDK];

  f32x4 acc[4][2];
#pragma unroll
  for (int m = 0; m < 4; ++m)
#pragma unroll
    for (int n = 0; n < 2; ++n) acc[m][n] = (f32x4){0.f, 0.f, 0.f, 0.f};

  const int arow = tid >> 1, achk = (tid & 1) * 16;
  const int r_loc_a = rt * 128 + arow;
  const int slot_a = off_e + (r_loc_a < n_e ? r_loc_a : n_e - 1);
  const __bf16* ap = abuf + (size_t)slot_a * INTER + kbase + achk;
  const bool isB = (tid < 128);
  const int bcq = (tid & 127) >> 3, bkq = tid & 7;
  const float* w2p =
      w2 + (size_t)e * INTER * HID + (size_t)(kbase + bkq * 4) * HID + col0 + bcq * 4;

  const int lr = lane & 15, lg = lane >> 4;

  bf16x8 av[2];
  float4 bv[4];
#define G2_LOAD(K0)                                                            \
  {                                                                            \
    av[0] = *(const bf16x8*)(ap + (K0));                                       \
    av[1] = *(const bf16x8*)(ap + (K0) + 8);                                   \
    if (isB) {                                                                 \
      const float* p = w2p + (size_t)(K0)*HID;                                 \
      _Pragma("unroll") for (int r = 0; r < 4; ++r) bv[r] =                    \
          *(const float4*)(p + (size_t)r * HID);                               \
    }                                                                          \
  }
#define G2_STORE(BUF)                                                          \
  {                                                                            \
    *(bf16x8*)&aL[BUF][arow][achk] = av[0];                                    \
    *(bf16x8*)&aL[BUF][arow][achk + 8] = av[1];                                \
    if (isB) TRANSPOSE_STORE(bL[BUF], bv[0], bv[1], bv[2], bv[3], bcq * 4, bkq * 4); \
  }

  const int NT = KCHUNK / BK;  // 32
  G2_LOAD(0);
  G2_STORE(0);
  __syncthreads();
#pragma unroll 1
  for (int t = 0; t < NT; ++t) {
    const int cur = t & 1, nxt = cur ^ 1;
    if (t + 1 < NT) G2_LOAD((t + 1) * BK);
    bf16x8 af[4], bf[2];
#pragma unroll
    for (int m = 0; m < 4; ++m) af[m] = *(const bf16x8*)&aL[cur][wr + m * 16 + lr][lg * 8];
#pragma unroll
    for (int n = 0; n < 2; ++n) bf[n] = *(const bf16x8*)&bL[cur][wc + n * 16 + lr][lg * 8];
#pragma unroll
    for (int m = 0; m < 4; ++m)
#pragma unroll
      for (int n = 0; n < 2; ++n)
        acc[m][n] = __builtin_amdgcn_mfma_f32_16x16x32_bf16(af[m], bf[n], acc[m][n], 0, 0, 0);
    if (t + 1 < NT) G2_STORE(nxt);
    __syncthreads();
  }
#undef G2_LOAD
#undef G2_STORE

  float* ysk = yslot + (size_t)sk * NSLOT * HID;
#pragma unroll
  for (int m = 0; m < 4; ++m)
#pragma unroll
    for (int n = 0; n < 2; ++n) {
      int col = col0 + wc + n * 16 + lr;
#pragma unroll
      for (int r = 0; r < 4; ++r) {
        int row_loc = rt * 128 + wr + m * 16 + lg * 4 + r;
        if (row_loc < n_e) {
          int slot = off_e + row_loc;
          ysk[(size_t)slot * HID + col] = gate_of[slot] * acc[m][n][r];
        }
      }
    }
}

// ---------------- combine ----------------
__global__ void moe_combine(const float* __restrict__ yslot, const int* __restrict__ slot_of,
                            float* __restrict__ out) {
  int i = blockIdx.x * blockDim.x + threadIdx.x;
  const int N4 = T_TOK * HID / 4;
  if (i >= N4) return;
  int t = i >> 8;
  int c4 = i & 255;
  int sA = slot_of[2 * t];
  int sB = slot_of[2 * t + 1];
  const float4* ys0 = (const float4*)yslot;
  const float4* ys1 = (const float4*)(yslot + (size_t)NSLOT * HID);
  float4 a = ys0[(size_t)sA * 256 + c4];
  float4 b = ys0[(size_t)sB * 256 + c4];
  float4 c = ys1[(size_t)sA * 256 + c4];
  float4 d = ys1[(size_t)sB * 256 + c4];
  float4 s;
  s.x = ((a.x + b.x) + c.x) + d.x;
  s.y = ((a.y + b.y) + c.y) + d.y;
  s.z = ((a.z + b.z) + c.z) + d.z;
  s.w = ((a.w + b.w) + c.w) + d.w;
  ((float4*)out)[i] = s;
}

// ---------------- launch ----------------
extern "C" void kernel_launch(void* const* d_in, const int* in_sizes, int n_in,
                              void* d_out, int out_size, void* d_ws, size_t ws_size,
                              hipStream_t stream) {
  const float* x = (const float*)d_in[0];
  const float* logits = (const float*)d_in[1];
  const float* w1 = (const float*)d_in[2];
  const float* w3 = (const float*)d_in[3];
  const float* w2 = (const float*)d_in[4];
  float* out = (float*)d_out;
  char* ws = (char*)d_ws;

  int* counts = (int*)(ws + WS_COUNTS);
  int* offsets = (int*)(ws + WS_OFFSETS);
  int* t_expert = (int*)(ws + WS_TEXPERT);
  float* t_gate = (float*)(ws + WS_TGATE);
  int* t_rank = (int*)(ws + WS_TRANK);
  int* token_of = (int*)(ws + WS_TOKEN_OF);
  float* gate_of = (float*)(ws + WS_GATE_OF);
  int* slot_of = (int*)(ws + WS_SLOT_OF);
  int* tile_e = (int*)(ws + WS_TILE_E);
  int* tile_r = (int*)(ws + WS_TILE_R);
  int* n_tiles = (int*)(ws + WS_NTILES);
  __bf16* abuf = (__bf16*)(ws + WS_ABUF);
  float* yslot = (float*)(ws + WS_YS);
  __bf16* xg = (__bf16*)(ws + WS_YS);  // alias: xg dead before gemm2 writes ys

  hipMemsetAsync(counts, 0, 64, stream);
  moe_router<<<dim3(4), dim3(256), 0, stream>>>(logits, counts, t_expert, t_gate, t_rank);
  moe_assign<<<dim3(1), dim3(256), 0, stream>>>(counts, offsets, t_expert, t_gate, t_rank,
                                                token_of, gate_of, slot_of, tile_e, tile_r,
                                                n_tiles);
  moe_xgather<<<dim3(NSLOT * (HID / 8) / 256), dim3(256), 0, stream>>>(x, token_of, xg);
  dim3 g1grid(INTER / 64, MAXTILES);
  // Ablation variants (outputs fully overwritten by the real pass below):
  moe_gemm1<1><<<g1grid, dim3(256), 0, stream>>>(xg, w1, w3, offsets, counts, tile_e, tile_r,
                                                 n_tiles, abuf);
  moe_gemm1<2><<<g1grid, dim3(256), 0, stream>>>(xg, w1, w3, offsets, counts, tile_e, tile_r,
                                                 n_tiles, abuf);
  // Real pass:
  moe_gemm1<0><<<g1grid, dim3(256), 0, stream>>>(xg, w1, w3, offsets, counts, tile_e, tile_r,
                                                 n_tiles, abuf);
  moe_gemm2<<<dim3(HID / 64, MAXTILES, SPLITK), dim3(256), 0, stream>>>(
      abuf, w2, offsets, counts, gate_of, tile_e, tile_r, n_tiles, yslot);
  moe_combine<<<dim3((T_TOK * HID / 4 + 255) / 256), dim3(256), 0, stream>>>(yslot, slot_of,
                                                                             out);
}

// Round 15
// 111.655 us; speedup vs baseline: 2.0709x; 2.0709x over previous
//
#include <hip/hip_runtime.h>

#define T_TOK 1024
#define NEXP 8
#define HID 1024
#define INTER 2048
#define SLOT_CAP 2176
#define NSLOT 2048
#define MAXTILES 24  // sum ceil(n_e/128) <= 23

#define BK 32
#define SPLITK 2
#define KCHUNK (INTER / SPLITK)  // 1024

typedef __bf16 bf16x8 __attribute__((ext_vector_type(8)));
typedef float f32x4 __attribute__((ext_vector_type(4)));

// async global->LDS DMA, 16B per lane; dest = wave-uniform base + lane*16
typedef const __attribute__((address_space(1))) void gv_t;
typedef __attribute__((address_space(3))) void lv_t;
static __device__ __forceinline__ void dma16(const void* g, void* l) {
  __builtin_amdgcn_global_load_lds((gv_t*)g, (lv_t*)l, 16, 0, 0);
}
#define VMW(N) asm volatile("s_waitcnt vmcnt(" #N ")" ::: "memory")
#define LKW() asm volatile("s_waitcnt lgkmcnt(0)" ::: "memory")

// ---- workspace layout (bytes) ----
#define WS_COUNTS 0
#define WS_OFFSETS 64
#define WS_TEXPERT 128
#define WS_TGATE (WS_TEXPERT + T_TOK * 2 * 4)
#define WS_TRANK (WS_TGATE + T_TOK * 2 * 4)
#define WS_TOKEN_OF (WS_TRANK + T_TOK * 2 * 4)
#define WS_GATE_OF (WS_TOKEN_OF + SLOT_CAP * 4)
#define WS_SLOT_OF (WS_GATE_OF + SLOT_CAP * 4)
#define WS_TILE_E (WS_SLOT_OF + T_TOK * 2 * 4)
#define WS_TILE_R (WS_TILE_E + 256)
#define WS_NTILES (WS_TILE_R + 256)
#define WS_ABUF 65536                           // bf16 a[SLOT_CAP][INTER]
#define WS_YS (WS_ABUF + SLOT_CAP * INTER * 2)  // fp32 ys[SPLITK][NSLOT][HID]
// xg (bf16 [SLOT_CAP][HID]) aliases YS: consumed by gemm1 before gemm2 writes ys.

// ---------------- router: softmax + top-2 ----------------
__global__ void moe_router(const float* __restrict__ logits, int* __restrict__ counts,
                           int* __restrict__ t_expert, float* __restrict__ t_gate,
                           int* __restrict__ t_rank) {
  int t = blockIdx.x * blockDim.x + threadIdx.x;
  if (t >= T_TOK) return;
  float l[NEXP];
  float mx = -1e30f;
#pragma unroll
  for (int e = 0; e < NEXP; ++e) {
    l[e] = logits[t * NEXP + e];
    mx = fmaxf(mx, l[e]);
  }
  float s = 0.f;
#pragma unroll
  for (int e = 0; e < NEXP; ++e) {
    l[e] = __expf(l[e] - mx);
    s += l[e];
  }
  float inv = 1.f / s;
  int i0 = 0;
#pragma unroll
  for (int e = 1; e < NEXP; ++e)
    if (l[e] > l[i0]) i0 = e;
  int i1 = (i0 == 0) ? 1 : 0;
#pragma unroll
  for (int e = 0; e < NEXP; ++e)
    if (e != i0 && e != i1 && l[e] > l[i1]) i1 = e;
  int es[2] = {i0, i1};
#pragma unroll
  for (int k = 0; k < 2; ++k) {
    int e = es[k];
    int r = atomicAdd(&counts[e], 1);
    int p = t * 2 + k;
    t_expert[p] = e;
    t_gate[p] = l[e] * inv;
    t_rank[p] = r;
  }
}

// ---------------- assign ----------------
__global__ void moe_assign(const int* __restrict__ counts, int* __restrict__ offsets,
                           const int* __restrict__ t_expert, const float* __restrict__ t_gate,
                           const int* __restrict__ t_rank, int* __restrict__ token_of,
                           float* __restrict__ gate_of, int* __restrict__ slot_of,
                           int* __restrict__ tile_e, int* __restrict__ tile_r,
                           int* __restrict__ n_tiles) {
  __shared__ int off_s[NEXP];
  if (threadIdx.x == 0) {
    int s = 0, nt = 0;
    for (int e = 0; e < NEXP; ++e) {
      off_s[e] = s;
      offsets[e] = s;
      int ntile = (counts[e] + 127) >> 7;
      for (int r = 0; r < ntile; ++r) {
        tile_e[nt] = e;
        tile_r[nt] = r;
        ++nt;
      }
      s += counts[e];
    }
    *n_tiles = nt;
  }
  __syncthreads();
  for (int p = threadIdx.x; p < T_TOK * 2; p += blockDim.x) {
    int e = t_expert[p];
    int slot = off_s[e] + t_rank[p];
    token_of[slot] = p >> 1;
    gate_of[slot] = t_gate[p];
    slot_of[p] = slot;
  }
}

// ---------------- xgather: xg[slot] = bf16(x[token_of[slot]]) ----------------
__global__ void moe_xgather(const float* __restrict__ x, const int* __restrict__ token_of,
                            __bf16* __restrict__ xg) {
  int idx = blockIdx.x * blockDim.x + threadIdx.x;
  int slot = idx >> 7;
  int c = (idx & 127) * 8;
  const float* src = x + (size_t)token_of[slot] * HID + c;
  float4 v0 = *(const float4*)src;
  float4 v1 = *(const float4*)(src + 4);
  bf16x8 o = {(__bf16)v0.x, (__bf16)v0.y, (__bf16)v0.z, (__bf16)v0.w,
              (__bf16)v1.x, (__bf16)v1.y, (__bf16)v1.z, (__bf16)v1.w};
  *(bf16x8*)&xg[(size_t)slot * HID + c] = o;
}

// ======================= GEMM1 =======================
// 256 threads, 4 waves (2M x 2N), BM=128, BN=64, wave tile 64x32.
// 2-stage LDS ring filled by global_load_lds DMA (no reg staging):
//   stage layout (24 KB): A bf16 [128 rows][64B]   at +0
//                         B1 fp32 [32 k][256B]      at +8192 (granule-XOR-swizzled)
//                         B3 fp32 [32 k][256B]      at +16384
// Counted vmcnt(6): consume stage t while stage t+1's 6 DMAs/wave stay in flight.
__global__ __launch_bounds__(256, 3) void moe_gemm1(
    const __bf16* __restrict__ xg, const float* __restrict__ w1, const float* __restrict__ w3,
    const int* __restrict__ offsets, const int* __restrict__ counts,
    const int* __restrict__ tile_e, const int* __restrict__ tile_r,
    const int* __restrict__ n_tiles, __bf16* __restrict__ abuf) {
  if ((int)blockIdx.y >= *n_tiles) return;
  const int e = tile_e[blockIdx.y];
  const int rt = tile_r[blockIdx.y];
  const int n_e = counts[e];
  const int off_e = offsets[e];
  const int col0 = blockIdx.x * 64;
  const int tid = threadIdx.x;
  const int lane = tid & 63;
  const int w = tid >> 6;
  const int wr = (w >> 1) * 64;
  const int wc = (w & 1) * 32;
  const int lr = lane & 15, lg = lane >> 4;

  __shared__ __align__(16) unsigned char sm[2 * 24576];

  f32x4 acc_h[4][2], acc_u[4][2];
#pragma unroll
  for (int m = 0; m < 4; ++m)
#pragma unroll
    for (int n = 0; n < 2; ++n) {
      acc_h[m][n] = (f32x4){0.f, 0.f, 0.f, 0.f};
      acc_u[m][n] = (f32x4){0.f, 0.f, 0.f, 0.f};
    }

  // ---- per-thread DMA source pointers (2 A chunks + 2 B1 + 2 B3 per wave) ----
  // A chunk c (c = w*2+j): lane covers row c*16 + (lane>>2), 16B seg (lane&3).
  const int c0 = w * 2;
  const __bf16* aSrc[2];
#pragma unroll
  for (int j = 0; j < 2; ++j) {
    int row = (c0 + j) * 16 + (lane >> 2);
    int r_loc = rt * 128 + row;
    int slot = off_e + (r_loc < n_e ? r_loc : n_e - 1);
    aSrc[j] = xg + (size_t)slot * HID + (lane & 3) * 8;
  }
  // B chunk c: lane covers k-row c*4 + (lane>>4), dest granule lane&15;
  // source granule = destg ^ ((k>>3)&3)  (XOR swizzle, applied on source).
  const float* b1Src[2];
  const float* b3Src[2];
#pragma unroll
  for (int j = 0; j < 2; ++j) {
    int kr = (c0 + j) * 4 + (lane >> 4);
    int gsrc = (lane & 15) ^ ((kr >> 3) & 3);
    size_t rowoff = (size_t)kr * INTER + col0 + gsrc * 4;
    b1Src[j] = w1 + (size_t)e * HID * INTER + rowoff;
    b3Src[j] = w3 + (size_t)e * HID * INTER + rowoff;
  }

#define G1_ISSUE(S, K0)                                                        \
  {                                                                            \
    unsigned char* base = sm + (S)*24576;                                      \
    dma16(aSrc[0] + (K0), base + (c0 + 0) * 1024);                             \
    dma16(aSrc[1] + (K0), base + (c0 + 1) * 1024);                             \
    dma16(b1Src[0] + (size_t)(K0)*INTER, base + 8192 + (c0 + 0) * 1024);       \
    dma16(b1Src[1] + (size_t)(K0)*INTER, base + 8192 + (c0 + 1) * 1024);       \
    dma16(b3Src[0] + (size_t)(K0)*INTER, base + 16384 + (c0 + 0) * 1024);      \
    dma16(b3Src[1] + (size_t)(K0)*INTER, base + 16384 + (c0 + 1) * 1024);      \
  }

  // B fragment: 8 fp32 at k=lg*8+j, col=wc+n*16+lr, swizzled granule (cg^lg)
#define G1_BFRAG(dstf, matoff, N)                                              \
  bf16x8 dstf;                                                                 \
  {                                                                            \
    int col = wc + (N)*16 + lr;                                                \
    int boff = lg * 2048 + (((col >> 2) ^ lg) << 4) + ((col & 3) << 2);        \
    const unsigned char* bb = base + (matoff) + boff;                          \
    float v0 = *(const float*)(bb + 0 * 256), v1 = *(const float*)(bb + 1 * 256); \
    float v2 = *(const float*)(bb + 2 * 256), v3 = *(const float*)(bb + 3 * 256); \
    float v4 = *(const float*)(bb + 4 * 256), v5 = *(const float*)(bb + 5 * 256); \
    float v6 = *(const float*)(bb + 6 * 256), v7 = *(const float*)(bb + 7 * 256); \
    dstf = (bf16x8){(__bf16)v0, (__bf16)v1, (__bf16)v2, (__bf16)v3,            \
                    (__bf16)v4, (__bf16)v5, (__bf16)v6, (__bf16)v7};           \
  }

  const int NT = HID / BK;  // 32
  G1_ISSUE(0, 0);
  G1_ISSUE(1, BK);
  VMW(6);
  __builtin_amdgcn_s_barrier();  // stage0 ready (stage1 in flight)

#pragma unroll 1
  for (int t = 0; t < NT; ++t) {
    const int s = t & 1;
    const unsigned char* base = sm + s * 24576;
    bf16x8 af[4];
#pragma unroll
    for (int m = 0; m < 4; ++m)
      af[m] = *(const bf16x8*)(base + (wr + m * 16 + lr) * 64 + lg * 16);
    G1_BFRAG(bf1a, 8192, 0);
    G1_BFRAG(bf1b, 8192, 1);
    G1_BFRAG(bf3a, 16384, 0);
    G1_BFRAG(bf3b, 16384, 1);
#pragma unroll
    for (int m = 0; m < 4; ++m) {
      acc_h[m][0] = __builtin_amdgcn_mfma_f32_16x16x32_bf16(af[m], bf1a, acc_h[m][0], 0, 0, 0);
      acc_h[m][1] = __builtin_amdgcn_mfma_f32_16x16x32_bf16(af[m], bf1b, acc_h[m][1], 0, 0, 0);
      acc_u[m][0] = __builtin_amdgcn_mfma_f32_16x16x32_bf16(af[m], bf3a, acc_u[m][0], 0, 0, 0);
      acc_u[m][1] = __builtin_amdgcn_mfma_f32_16x16x32_bf16(af[m], bf3b, acc_u[m][1], 0, 0, 0);
    }
    LKW();
    __builtin_amdgcn_s_barrier();  // all waves done reading stage s
    if (t + 2 < NT) {
      G1_ISSUE(s, (t + 2) * BK);  // refill stage s
      VMW(6);                     // stage t+1 done; t+2 stays in flight
    } else {
      VMW(0);
    }
    __builtin_amdgcn_s_barrier();  // stage t+1 visible to all
  }
#undef G1_ISSUE
#undef G1_BFRAG

  // epilogue: a = silu(h) * u, store bf16
#pragma unroll
  for (int m = 0; m < 4; ++m)
#pragma unroll
    for (int n = 0; n < 2; ++n) {
      int col = col0 + wc + n * 16 + lr;
#pragma unroll
      for (int r = 0; r < 4; ++r) {
        int row_loc = rt * 128 + wr + m * 16 + lg * 4 + r;
        if (row_loc < n_e) {
          float h = acc_h[m][n][r];
          float u = acc_u[m][n][r];
          float a = h / (1.f + __expf(-h)) * u;
          abuf[(size_t)(off_e + row_loc) * INTER + col] = (__bf16)a;
        }
      }
    }
}

// ======================= GEMM2 =======================
// Same DMA-ring scheme; stage (16 KB): A bf16 [128][64B] at +0, B=w2 fp32 [32][256B] at +8192.
// 4 DMAs per wave per stage -> vmcnt(4).
__global__ __launch_bounds__(256, 4) void moe_gemm2(
    const __bf16* __restrict__ abuf, const float* __restrict__ w2,
    const int* __restrict__ offsets, const int* __restrict__ counts,
    const float* __restrict__ gate_of, const int* __restrict__ tile_e,
    const int* __restrict__ tile_r, const int* __restrict__ n_tiles,
    float* __restrict__ yslot) {
  if ((int)blockIdx.y >= *n_tiles) return;
  const int e = tile_e[blockIdx.y];
  const int rt = tile_r[blockIdx.y];
  const int sk = blockIdx.z;
  const int n_e = counts[e];
  const int off_e = offsets[e];
  const int col0 = blockIdx.x * 64;
  const int kbase = sk * KCHUNK;
  const int tid = threadIdx.x;
  const int lane = tid & 63;
  const int w = tid >> 6;
  const int wr = (w >> 1) * 64;
  const int wc = (w & 1) * 32;
  const int lr = lane & 15, lg = lane >> 4;

  __shared__ __align__(16) unsigned char sm[2 * 16384];

  f32x4 acc[4][2];
#pragma unroll
  for (int m = 0; m < 4; ++m)
#pragma unroll
    for (int n = 0; n < 2; ++n) acc[m][n] = (f32x4){0.f, 0.f, 0.f, 0.f};

  const int c0 = w * 2;
  const __bf16* aSrc[2];
#pragma unroll
  for (int j = 0; j < 2; ++j) {
    int row = (c0 + j) * 16 + (lane >> 2);
    int r_loc = rt * 128 + row;
    int slot = off_e + (r_loc < n_e ? r_loc : n_e - 1);
    aSrc[j] = abuf + (size_t)slot * INTER + kbase + (lane & 3) * 8;
  }
  const float* bSrc[2];
#pragma unroll
  for (int j = 0; j < 2; ++j) {
    int kr = (c0 + j) * 4 + (lane >> 4);
    int gsrc = (lane & 15) ^ ((kr >> 3) & 3);
    bSrc[j] = w2 + (size_t)e * INTER * HID + (size_t)(kbase + kr) * HID + col0 + gsrc * 4;
  }

#define G2_ISSUE(S, K0)                                                        \
  {                                                                            \
    unsigned char* base = sm + (S)*16384;                                      \
    dma16(aSrc[0] + (K0), base + (c0 + 0) * 1024);                             \
    dma16(aSrc[1] + (K0), base + (c0 + 1) * 1024);                             \
    dma16(bSrc[0] + (size_t)(K0)*HID, base + 8192 + (c0 + 0) * 1024);          \
    dma16(bSrc[1] + (size_t)(K0)*HID, base + 8192 + (c0 + 1) * 1024);          \
  }
#define G2_BFRAG(dstf, N)                                                      \
  bf16x8 dstf;                                                                 \
  {                                                                            \
    int col = wc + (N)*16 + lr;                                                \
    int boff = lg * 2048 + (((col >> 2) ^ lg) << 4) + ((col & 3) << 2);        \
    const unsigned char* bb = base + 8192 + boff;                              \
    float v0 = *(const float*)(bb + 0 * 256), v1 = *(const float*)(bb + 1 * 256); \
    float v2 = *(const float*)(bb + 2 * 256), v3 = *(const float*)(bb + 3 * 256); \
    float v4 = *(const float*)(bb + 4 * 256), v5 = *(const float*)(bb + 5 * 256); \
    float v6 = *(const float*)(bb + 6 * 256), v7 = *(const float*)(bb + 7 * 256); \
    dstf = (bf16x8){(__bf16)v0, (__bf16)v1, (__bf16)v2, (__bf16)v3,            \
                    (__bf16)v4, (__bf16)v5, (__bf16)v6, (__bf16)v7};           \
  }

  const int NT = KCHUNK / BK;  // 32
  G2_ISSUE(0, 0);
  G2_ISSUE(1, BK);
  VMW(4);
  __builtin_amdgcn_s_barrier();

#pragma unroll 1
  for (int t = 0; t < NT; ++t) {
    const int s = t & 1;
    const unsigned char* base = sm + s * 16384;
    bf16x8 af[4];
#pragma unroll
    for (int m = 0; m < 4; ++m)
      af[m] = *(const bf16x8*)(base + (wr + m * 16 + lr) * 64 + lg * 16);
    G2_BFRAG(bfa, 0);
    G2_BFRAG(bfb, 1);
#pragma unroll
    for (int m = 0; m < 4; ++m) {
      acc[m][0] = __builtin_amdgcn_mfma_f32_16x16x32_bf16(af[m], bfa, acc[m][0], 0, 0, 0);
      acc[m][1] = __builtin_amdgcn_mfma_f32_16x16x32_bf16(af[m], bfb, acc[m][1], 0, 0, 0);
    }
    LKW();
    __builtin_amdgcn_s_barrier();
    if (t + 2 < NT) {
      G2_ISSUE(s, (t + 2) * BK);
      VMW(4);
    } else {
      VMW(0);
    }
    __builtin_amdgcn_s_barrier();
  }
#undef G2_ISSUE
#undef G2_BFRAG

  // epilogue: plain stores, each (sk,slot,col) written exactly once
  float* ysk = yslot + (size_t)sk * NSLOT * HID;
#pragma unroll
  for (int m = 0; m < 4; ++m)
#pragma unroll
    for (int n = 0; n < 2; ++n) {
      int col = col0 + wc + n * 16 + lr;
#pragma unroll
      for (int r = 0; r < 4; ++r) {
        int row_loc = rt * 128 + wr + m * 16 + lg * 4 + r;
        if (row_loc < n_e) {
          int slot = off_e + row_loc;
          ysk[(size_t)slot * HID + col] = gate_of[slot] * acc[m][n][r];
        }
      }
    }
}

// ---------------- combine ----------------
__global__ void moe_combine(const float* __restrict__ yslot, const int* __restrict__ slot_of,
                            float* __restrict__ out) {
  int i = blockIdx.x * blockDim.x + threadIdx.x;
  const int N4 = T_TOK * HID / 4;
  if (i >= N4) return;
  int t = i >> 8;
  int c4 = i & 255;
  int sA = slot_of[2 * t];
  int sB = slot_of[2 * t + 1];
  const float4* ys0 = (const float4*)yslot;
  const float4* ys1 = (const float4*)(yslot + (size_t)NSLOT * HID);
  float4 a = ys0[(size_t)sA * 256 + c4];
  float4 b = ys0[(size_t)sB * 256 + c4];
  float4 c = ys1[(size_t)sA * 256 + c4];
  float4 d = ys1[(size_t)sB * 256 + c4];
  float4 s;
  s.x = ((a.x + b.x) + c.x) + d.x;
  s.y = ((a.y + b.y) + c.y) + d.y;
  s.z = ((a.z + b.z) + c.z) + d.z;
  s.w = ((a.w + b.w) + c.w) + d.w;
  ((float4*)out)[i] = s;
}

// ---------------- launch ----------------
extern "C" void kernel_launch(void* const* d_in, const int* in_sizes, int n_in,
                              void* d_out, int out_size, void* d_ws, size_t ws_size,
                              hipStream_t stream) {
  const float* x = (const float*)d_in[0];
  const float* logits = (const float*)d_in[1];
  const float* w1 = (const float*)d_in[2];
  const float* w3 = (const float*)d_in[3];
  const float* w2 = (const float*)d_in[4];
  float* out = (float*)d_out;
  char* ws = (char*)d_ws;

  int* counts = (int*)(ws + WS_COUNTS);
  int* offsets = (int*)(ws + WS_OFFSETS);
  int* t_expert = (int*)(ws + WS_TEXPERT);
  float* t_gate = (float*)(ws + WS_TGATE);
  int* t_rank = (int*)(ws + WS_TRANK);
  int* token_of = (int*)(ws + WS_TOKEN_OF);
  float* gate_of = (float*)(ws + WS_GATE_OF);
  int* slot_of = (int*)(ws + WS_SLOT_OF);
  int* tile_e = (int*)(ws + WS_TILE_E);
  int* tile_r = (int*)(ws + WS_TILE_R);
  int* n_tiles = (int*)(ws + WS_NTILES);
  __bf16* abuf = (__bf16*)(ws + WS_ABUF);
  float* yslot = (float*)(ws + WS_YS);
  __bf16* xg = (__bf16*)(ws + WS_YS);  // alias: xg dead before gemm2 writes ys

  hipMemsetAsync(counts, 0, 64, stream);
  moe_router<<<dim3(4), dim3(256), 0, stream>>>(logits, counts, t_expert, t_gate, t_rank);
  moe_assign<<<dim3(1), dim3(256), 0, stream>>>(counts, offsets, t_expert, t_gate, t_rank,
                                                token_of, gate_of, slot_of, tile_e, tile_r,
                                                n_tiles);
  moe_xgather<<<dim3(NSLOT * (HID / 8) / 256), dim3(256), 0, stream>>>(x, token_of, xg);
  moe_gemm1<<<dim3(INTER / 64, MAXTILES), dim3(256), 0, stream>>>(
      xg, w1, w3, offsets, counts, tile_e, tile_r, n_tiles, abuf);
  moe_gemm2<<<dim3(HID / 64, MAXTILES, SPLITK), dim3(256), 0, stream>>>(
      abuf, w2, offsets, counts, gate_of, tile_e, tile_r, n_tiles, yslot);
  moe_combine<<<dim3((T_TOK * HID / 4 + 255) / 256), dim3(256), 0, stream>>>(yslot, slot_of,
                                                                             out);
}